// Round 15
// baseline (27.988 us; speedup 1.0000x reference)
//
#include <hip/hip_runtime.h>

#define NF 17
#define NN 23
#define ED 16
#define BLK 1024
#define RPP 256      // rows per pass = BLK/4
#define RPB 512      // rows per block (2 passes); grid*RPB == nrows exactly
#define SROWS 862    // packed rows of the 14 small-vocab fields
#define SSTR 20      // padded floats per LDS row (80 B)

typedef int   int4u    __attribute__((ext_vector_type(4), aligned(4)));
typedef float float4u  __attribute__((ext_vector_type(4), aligned(4)));
typedef float float2u  __attribute__((ext_vector_type(2), aligned(4)));
typedef float float2v  __attribute__((ext_vector_type(2)));

// broadcast int k of the row from owner lane (k>>2), slot (k&3), to all 4
// lanes of the group. BitMode ds_swizzle: offset=(xor<<10)|(or<<5)|and;
// and=0x1C keeps group bits, or = k>>2 selects source lane.
#define SWZ(slotval, j) __builtin_amdgcn_ds_swizzle((slotval), ((j) << 5) | 0x1C)

// packed accumulate: 2x v_pk_add_f32 + 2x v_pk_fma_f32 per field
__device__ __forceinline__ void acc4(const float4 v, float2v& sa, float2v& sb,
                                     float2v& sq2) {
    const float2v lo = {v.x, v.y};
    const float2v hi = {v.z, v.w};
    sa += lo;
    sb += hi;
    sq2 += lo * lo;
    sq2 += hi * hi;
}

__global__ __launch_bounds__(BLK, 8) void ffm_fwd_kernel(
    const int* __restrict__ x_cat,
    const float* __restrict__ x_num,
    const float* __restrict__ table,
    const float* __restrict__ W_num,
    const float* __restrict__ bias,
    float* __restrict__ out,
    int nrows)
{
    __shared__ float tab[SROWS * SSTR];   // 68,960 B -> 2 blocks/CU
    __shared__ float wsum[24];            // padded; wsum[23] = 0

    const int tid = threadIdx.x;
    const int rl  = tid >> 2;   // local row within pass
    const int g   = tid & 3;    // dim-group: dims [4g, 4g+4)
    const int wb  = 6 * g;

    const int row0 = blockIdx.x * RPB + rl;    // grid*RPB == nrows, no guards
    const int row1 = row0 + RPP;

    // ===== PROLOGUE: lane-split x_cat for BOTH passes; pass-0 gathers only =====
    const int* xc0 = x_cat + (size_t)row0 * NF;
    const int4u av = *(const int4u*)(xc0 + g * 4);
    const int  a16 = xc0[16];
    const int* xc1 = x_cat + (size_t)row1 * NF;
    const int4u cv = *(const int4u*)(xc1 + g * 4);   // cheap (5 regs) to hold
    const int  c16 = xc1[16];

    // pass-0's 3 gathers issue pre-staging (proven safe: 12 regs across barrier)
    const int bc4  = SWZ(av.x, 1);   // f4  (k=4:  slot x, lane 1)
    const int bc10 = SWZ(av.z, 2);   // f10 (k=10: slot z, lane 2)
    const int bc14 = SWZ(av.z, 3);   // f14 (k=14: slot z, lane 3)
    const float4 gv00 = *(const float4*)(table + (size_t)(bc4  +     653) * ED + g * 4);
    const float4 gv01 = *(const float4*)(table + (size_t)(bc10 + 1000787) * ED + g * 4);
    const float4 gv02 = *(const float4*)(table + (size_t)(bc14 + 1001846) * ED + g * 4);

    // pass-0 numeric slice
    const float* xp0 = x_num + (size_t)row0 * NN;
    const float4u xa0 = *(const float4u*)(xp0 + wb);
    float xb0_0, xb1_0;
    if (g < 3) { const float2u t = *(const float2u*)(xp0 + wb + 4); xb0_0 = t.x; xb1_0 = t.y; }
    else       { xb0_0 = xp0[22]; xb1_0 = 0.f; }

    if (tid < 24) {
        float a = 0.f;
        if (tid < NN) {
            #pragma unroll
            for (int d = 0; d < ED; ++d) a += W_num[d * NN + tid];
        }
        wsum[tid] = a;
    }

    // ---- Stage the 14 small-vocab fields (862 rows, 55 KB): simple loop ----
    for (int i = tid; i < SROWS * 4; i += BLK) {
        const int r = i >> 2, q = i & 3;
        const int d = (r < 653) ? 0 : (r < 787) ? 1000000 : (r < 845) ? 1001001 : 1003001;
        *(float4*)&tab[r * SSTR + q * 4] =
            *(const float4*)(table + (size_t)(r + d) * ED + q * 4);
    }
    __syncthreads();

    // ===== IMMEDIATELY post-barrier: issue pass-1 gathers (cv is resident).
    // Their ~500cyc latency is covered by pass-0's swizzles + LDS math below;
    // results do NOT cross the barrier, so no staging-phase pressure. =====
    const int dc4  = SWZ(cv.x, 1);
    const int dc10 = SWZ(cv.z, 2);
    const int dc14 = SWZ(cv.z, 3);
    const float4 gv10 = *(const float4*)(table + (size_t)(dc4  +     653) * ED + g * 4);
    const float4 gv11 = *(const float4*)(table + (size_t)(dc10 + 1000787) * ED + g * 4);
    const float4 gv12 = *(const float4*)(table + (size_t)(dc14 + 1001846) * ED + g * 4);

    // pass-1 x_num also in flight under pass-0 math
    const float* xp1 = x_num + (size_t)row1 * NN;
    const float4u xa1 = *(const float4u*)(xp1 + wb);
    float xb0_1, xb1_1;
    if (g < 3) { const float2u t = *(const float2u*)(xp1 + wb + 4); xb0_1 = t.x; xb1_1 = t.y; }
    else       { xb0_1 = xp1[22]; xb1_1 = 0.f; }

    const float b0 = bias[0];
    const float2v wp0 = {wsum[wb],     wsum[wb + 1]};
    const float2v wp1 = {wsum[wb + 2], wsum[wb + 3]};
    const float2v wp2 = {wsum[wb + 4], wsum[wb + 5]};

    // ========== PASS 0 (gathers resident since pre-staging) ==========
    {
        float2v lv = {0.f, 0.f};
        lv += float2v{xa0.x, xa0.y} * wp0;
        lv += float2v{xa0.z, xa0.w} * wp1;
        lv += float2v{xb0_0, xb1_0} * wp2;

        int pr[14];
        pr[0]  = SWZ(av.x, 0);         pr[1]  = 500 + SWZ(av.y, 0);
        pr[2]  = 550 + SWZ(av.z, 0);   pr[3]  = 650 + SWZ(av.w, 0);
        pr[4]  = 653 + SWZ(av.y, 1);   pr[5]  = 663 + SWZ(av.z, 1);
        pr[6]  = 683 + SWZ(av.w, 1);   pr[7]  = 783 + SWZ(av.x, 2);
        pr[8]  = 785 + SWZ(av.y, 2);   pr[9]  = 787 + SWZ(av.w, 2);
        pr[10] = 791 + SWZ(av.x, 3);   pr[11] = 795 + SWZ(av.y, 3);
        pr[12] = 845 + SWZ(av.w, 3);   pr[13] = 855 + a16;

        float2v sa = {0.f, 0.f}, sb = {0.f, 0.f}, sq2 = {0.f, 0.f};
        #pragma unroll
        for (int k = 0; k < 14; ++k)
            acc4(*(const float4*)&tab[pr[k] * SSTR + g * 4], sa, sb, sq2);

        acc4(gv00, sa, sb, sq2);
        acc4(gv01, sa, sb, sq2);
        acc4(gv02, sa, sb, sq2);

        const float s0 = sa.x, s1 = sa.y, s2 = sb.x, s3 = sb.y;
        const float sq = sq2.x + sq2.y;
        float contrib = (s0 + s1 + s2 + s3) + (lv.x + lv.y)
                      + 0.5f * ((s0 * s0 + s1 * s1 + s2 * s2 + s3 * s3) - sq);
        contrib += __shfl_xor(contrib, 1);
        contrib += __shfl_xor(contrib, 2);
        if (g == 0) out[row0] = b0 + contrib;
    }

    // ========== PASS 1 (gathers issued ~400cyc ago; mostly resident) ==========
    {
        int pr[14];
        pr[0]  = SWZ(cv.x, 0);         pr[1]  = 500 + SWZ(cv.y, 0);
        pr[2]  = 550 + SWZ(cv.z, 0);   pr[3]  = 650 + SWZ(cv.w, 0);
        pr[4]  = 653 + SWZ(cv.y, 1);   pr[5]  = 663 + SWZ(cv.z, 1);
        pr[6]  = 683 + SWZ(cv.w, 1);   pr[7]  = 783 + SWZ(cv.x, 2);
        pr[8]  = 785 + SWZ(cv.y, 2);   pr[9]  = 787 + SWZ(cv.w, 2);
        pr[10] = 791 + SWZ(cv.x, 3);   pr[11] = 795 + SWZ(cv.y, 3);
        pr[12] = 845 + SWZ(cv.w, 3);   pr[13] = 855 + c16;

        float2v lv = {0.f, 0.f};
        lv += float2v{xa1.x, xa1.y} * wp0;
        lv += float2v{xa1.z, xa1.w} * wp1;
        lv += float2v{xb0_1, xb1_1} * wp2;

        float2v sa = {0.f, 0.f}, sb = {0.f, 0.f}, sq2 = {0.f, 0.f};
        #pragma unroll
        for (int k = 0; k < 14; ++k)
            acc4(*(const float4*)&tab[pr[k] * SSTR + g * 4], sa, sb, sq2);

        acc4(gv10, sa, sb, sq2);
        acc4(gv11, sa, sb, sq2);
        acc4(gv12, sa, sb, sq2);

        const float s0 = sa.x, s1 = sa.y, s2 = sb.x, s3 = sb.y;
        const float sq = sq2.x + sq2.y;
        float contrib = (s0 + s1 + s2 + s3) + (lv.x + lv.y)
                      + 0.5f * ((s0 * s0 + s1 * s1 + s2 * s2 + s3 * s3) - sq);
        contrib += __shfl_xor(contrib, 1);
        contrib += __shfl_xor(contrib, 2);
        if (g == 0) out[row1] = b0 + contrib;
    }
}

extern "C" void kernel_launch(void* const* d_in, const int* in_sizes, int n_in,
                              void* d_out, int out_size, void* d_ws, size_t ws_size,
                              hipStream_t stream) {
    const int*   x_cat = (const int*)  d_in[0];
    const float* x_num = (const float*)d_in[1];
    const float* table = (const float*)d_in[2];
    const float* W_num = (const float*)d_in[3];
    const float* bias  = (const float*)d_in[4];
    float* out = (float*)d_out;

    const int nrows = out_size;                 // 262144
    const int grid = (nrows + RPB - 1) / RPB;   // 512
    ffm_fwd_kernel<<<grid, BLK, 0, stream>>>(x_cat, x_num, table, W_num, bias, out, nrows);
}

// Round 16
// 26.027 us; speedup vs baseline: 1.0754x; 1.0754x over previous
//
#include <hip/hip_runtime.h>

#define NF 17
#define NN 23
#define ED 16
#define BLK 1024
#define RPP 256      // rows per pass = BLK/4
#define RPB 512      // rows per block (2 passes); grid*RPB == nrows exactly
#define SROWS 862    // packed rows of the 14 small-vocab fields
#define SSTR 16      // UNPADDED: global_load_lds needs linear dest; banks fixed by XOR swizzle

typedef int   int4u    __attribute__((ext_vector_type(4), aligned(4)));
typedef float float4u  __attribute__((ext_vector_type(4), aligned(4)));
typedef float float2u  __attribute__((ext_vector_type(2), aligned(4)));
typedef float float2v  __attribute__((ext_vector_type(2)));

// broadcast int k of the row from owner lane (k>>2), slot (k&3), to all 4
// lanes of the group. BitMode ds_swizzle: offset=(xor<<10)|(or<<5)|and.
#define SWZ(slotval, j) __builtin_amdgcn_ds_swizzle((slotval), ((j) << 5) | 0x1C)

// packed accumulate: 2x v_pk_add_f32 + 2x v_pk_fma_f32 per field
__device__ __forceinline__ void acc4(const float4 v, float2v& sa, float2v& sb,
                                     float2v& sq2) {
    const float2v lo = {v.x, v.y};
    const float2v hi = {v.z, v.w};
    sa += lo;
    sb += hi;
    sq2 += lo * lo;
    sq2 += hi * hi;
}

// swizzled LDS float-index of quad g of packed row p:
// quad stored at lds-slot (g ^ (p&3)); inverse applied at staging (involution).
__device__ __forceinline__ int ldsq(int p, int g) {
    return (p << 4) + (((g ^ p) & 3) << 2);
}

__global__ __launch_bounds__(BLK, 8) void ffm_fwd_kernel(
    const int* __restrict__ x_cat,
    const float* __restrict__ x_num,
    const float* __restrict__ table,
    const float* __restrict__ W_num,
    const float* __restrict__ bias,
    float* __restrict__ out,
    int nrows)
{
    __shared__ float tab[SROWS * SSTR];   // 55,168 B -> 2 blocks/CU
    __shared__ float wsum[24];            // padded; wsum[23] = 0

    const int tid = threadIdx.x;
    const int rl  = tid >> 2;   // local row within pass
    const int g   = tid & 3;    // dim-group: dims [4g, 4g+4)
    const int wb  = 6 * g;

    const int row0 = blockIdx.x * RPB + rl;    // grid*RPB == nrows, no guards
    const int row1 = row0 + RPP;

    // ===== PROLOGUE: lane-split x_cat for BOTH passes + ALL 6 gathers =====
    const int* xc0 = x_cat + (size_t)row0 * NF;
    const int4u av = *(const int4u*)(xc0 + g * 4);
    const int  a16 = xc0[16];
    const int* xc1 = x_cat + (size_t)row1 * NF;
    const int4u cv = *(const int4u*)(xc1 + g * 4);
    const int  c16 = xc1[16];

    const int bc4  = SWZ(av.x, 1);   // f4  (k=4:  slot x, lane 1)
    const int bc10 = SWZ(av.z, 2);   // f10 (k=10: slot z, lane 2)
    const int bc14 = SWZ(av.z, 3);   // f14 (k=14: slot z, lane 3)
    const int dc4  = SWZ(cv.x, 1);
    const int dc10 = SWZ(cv.z, 2);
    const int dc14 = SWZ(cv.z, 3);
    const float4 gv00 = *(const float4*)(table + (size_t)(bc4  +     653) * ED + g * 4);
    const float4 gv01 = *(const float4*)(table + (size_t)(bc10 + 1000787) * ED + g * 4);
    const float4 gv02 = *(const float4*)(table + (size_t)(bc14 + 1001846) * ED + g * 4);
    const float4 gv10 = *(const float4*)(table + (size_t)(dc4  +     653) * ED + g * 4);
    const float4 gv11 = *(const float4*)(table + (size_t)(dc10 + 1000787) * ED + g * 4);
    const float4 gv12 = *(const float4*)(table + (size_t)(dc14 + 1001846) * ED + g * 4);

    // pass-0 numeric slice
    const float* xp0 = x_num + (size_t)row0 * NN;
    const float4u xa0 = *(const float4u*)(xp0 + wb);
    float xb0_0, xb1_0;
    if (g < 3) { const float2u t = *(const float2u*)(xp0 + wb + 4); xb0_0 = t.x; xb1_0 = t.y; }
    else       { xb0_0 = xp0[22]; xb1_0 = 0.f; }

    if (tid < 24) {
        float a = 0.f;
        if (tid < NN) {
            #pragma unroll
            for (int d = 0; d < ED; ++d) a += W_num[d * NN + tid];
        }
        wsum[tid] = a;
    }

    // ---- Stage 862 rows via global_load_lds: zero VGPR round-trip.
    // LDS dest is linear (base + lane*16B); the quad permutation is applied on
    // the GLOBAL source address (q_glob = q_lds ^ (r&3)) and inverted on read.
    for (int i = tid; i < SROWS * 4; i += BLK) {
        const int r = i >> 2, ql = i & 3;
        const int qg = ql ^ (r & 3);
        const int d = (r < 653) ? 0 : (r < 787) ? 1000000 : (r < 845) ? 1001001 : 1003001;
        const float* src = table + (size_t)(r + d) * ED + qg * 4;
        __builtin_amdgcn_global_load_lds(
            (const __attribute__((address_space(1))) void*)src,
            (__attribute__((address_space(3))) void*)&tab[i * 4], 16, 0, 0);
    }
    __syncthreads();   // drains vmcnt: staging AND all 6 prologue gathers

    const float b0 = bias[0];
    const float2v wp0 = {wsum[wb],     wsum[wb + 1]};
    const float2v wp1 = {wsum[wb + 2], wsum[wb + 3]};
    const float2v wp2 = {wsum[wb + 4], wsum[wb + 5]};

    // ========== PASS 0 ==========
    {
        float2v lv = {0.f, 0.f};
        lv += float2v{xa0.x, xa0.y} * wp0;
        lv += float2v{xa0.z, xa0.w} * wp1;
        lv += float2v{xb0_0, xb1_0} * wp2;

        int pr[14];
        pr[0]  = SWZ(av.x, 0);         pr[1]  = 500 + SWZ(av.y, 0);
        pr[2]  = 550 + SWZ(av.z, 0);   pr[3]  = 650 + SWZ(av.w, 0);
        pr[4]  = 653 + SWZ(av.y, 1);   pr[5]  = 663 + SWZ(av.z, 1);
        pr[6]  = 683 + SWZ(av.w, 1);   pr[7]  = 783 + SWZ(av.x, 2);
        pr[8]  = 785 + SWZ(av.y, 2);   pr[9]  = 787 + SWZ(av.w, 2);
        pr[10] = 791 + SWZ(av.x, 3);   pr[11] = 795 + SWZ(av.y, 3);
        pr[12] = 845 + SWZ(av.w, 3);   pr[13] = 855 + a16;

        float2v sa = {0.f, 0.f}, sb = {0.f, 0.f}, sq2 = {0.f, 0.f};
        #pragma unroll
        for (int k = 0; k < 14; ++k)
            acc4(*(const float4*)&tab[ldsq(pr[k], g)], sa, sb, sq2);

        acc4(gv00, sa, sb, sq2);
        acc4(gv01, sa, sb, sq2);
        acc4(gv02, sa, sb, sq2);

        const float s0 = sa.x, s1 = sa.y, s2 = sb.x, s3 = sb.y;
        const float sq = sq2.x + sq2.y;
        float contrib = (s0 + s1 + s2 + s3) + (lv.x + lv.y)
                      + 0.5f * ((s0 * s0 + s1 * s1 + s2 * s2 + s3 * s3) - sq);
        contrib += __shfl_xor(contrib, 1);
        contrib += __shfl_xor(contrib, 2);
        if (g == 0) out[row0] = b0 + contrib;
    }

    // ---- pass-1 x_num ----
    const float* xp1 = x_num + (size_t)row1 * NN;
    const float4u xa1 = *(const float4u*)(xp1 + wb);
    float xb0_1, xb1_1;
    if (g < 3) { const float2u t = *(const float2u*)(xp1 + wb + 4); xb0_1 = t.x; xb1_1 = t.y; }
    else       { xb0_1 = xp1[22]; xb1_1 = 0.f; }

    // ========== PASS 1 (gathers resident since prologue) ==========
    {
        int pr[14];
        pr[0]  = SWZ(cv.x, 0);         pr[1]  = 500 + SWZ(cv.y, 0);
        pr[2]  = 550 + SWZ(cv.z, 0);   pr[3]  = 650 + SWZ(cv.w, 0);
        pr[4]  = 653 + SWZ(cv.y, 1);   pr[5]  = 663 + SWZ(cv.z, 1);
        pr[6]  = 683 + SWZ(cv.w, 1);   pr[7]  = 783 + SWZ(cv.x, 2);
        pr[8]  = 785 + SWZ(cv.y, 2);   pr[9]  = 787 + SWZ(cv.w, 2);
        pr[10] = 791 + SWZ(cv.x, 3);   pr[11] = 795 + SWZ(cv.y, 3);
        pr[12] = 845 + SWZ(cv.w, 3);   pr[13] = 855 + c16;

        float2v lv = {0.f, 0.f};
        lv += float2v{xa1.x, xa1.y} * wp0;
        lv += float2v{xa1.z, xa1.w} * wp1;
        lv += float2v{xb0_1, xb1_1} * wp2;

        float2v sa = {0.f, 0.f}, sb = {0.f, 0.f}, sq2 = {0.f, 0.f};
        #pragma unroll
        for (int k = 0; k < 14; ++k)
            acc4(*(const float4*)&tab[ldsq(pr[k], g)], sa, sb, sq2);

        acc4(gv10, sa, sb, sq2);
        acc4(gv11, sa, sb, sq2);
        acc4(gv12, sa, sb, sq2);

        const float s0 = sa.x, s1 = sa.y, s2 = sb.x, s3 = sb.y;
        const float sq = sq2.x + sq2.y;
        float contrib = (s0 + s1 + s2 + s3) + (lv.x + lv.y)
                      + 0.5f * ((s0 * s0 + s1 * s1 + s2 * s2 + s3 * s3) - sq);
        contrib += __shfl_xor(contrib, 1);
        contrib += __shfl_xor(contrib, 2);
        if (g == 0) out[row1] = b0 + contrib;
    }
}

extern "C" void kernel_launch(void* const* d_in, const int* in_sizes, int n_in,
                              void* d_out, int out_size, void* d_ws, size_t ws_size,
                              hipStream_t stream) {
    const int*   x_cat = (const int*)  d_in[0];
    const float* x_num = (const float*)d_in[1];
    const float* table = (const float*)d_in[2];
    const float* W_num = (const float*)d_in[3];
    const float* bias  = (const float*)d_in[4];
    float* out = (float*)d_out;

    const int nrows = out_size;                 // 262144
    const int grid = (nrows + RPB - 1) / RPB;   // 512
    ffm_fwd_kernel<<<grid, BLK, 0, stream>>>(x_cat, x_num, table, W_num, bias, out, nrows);
}

// Round 17
// 22.471 us; speedup vs baseline: 1.2455x; 1.1582x over previous
//
#include <hip/hip_runtime.h>

#define NF 17
#define NN 23
#define ED 16
#define BLK 1024
#define RPP 256      // rows per pass = BLK/4
#define RPB 512      // rows per block (2 passes); grid*RPB == nrows exactly
#define SROWS 862    // packed rows of the 14 small-vocab fields
#define SSTR 18      // floats per LDS row (72 B): 16 even start-banks, 8B-aligned

typedef int   int4u    __attribute__((ext_vector_type(4), aligned(4)));
typedef float float4u  __attribute__((ext_vector_type(4), aligned(4)));
typedef float float2u  __attribute__((ext_vector_type(2), aligned(4)));
typedef float float2v  __attribute__((ext_vector_type(2)));

// broadcast int k of the row from owner lane (k>>2), slot (k&3), to all 4
// lanes of the group. BitMode ds_swizzle: offset=(xor<<10)|(or<<5)|and.
#define SWZ(slotval, j) __builtin_amdgcn_ds_swizzle((slotval), ((j) << 5) | 0x1C)

// packed accumulate: 2x v_pk_add_f32 + 2x v_pk_fma_f32 per field
__device__ __forceinline__ void acc4(const float4 v, float2v& sa, float2v& sb,
                                     float2v& sq2) {
    const float2v lo = {v.x, v.y};
    const float2v hi = {v.z, v.w};
    sa += lo;
    sb += hi;
    sq2 += lo * lo;
    sq2 += hi * hi;
}

__global__ __launch_bounds__(BLK, 8) void ffm_fwd_kernel(
    const int* __restrict__ x_cat,
    const float* __restrict__ x_num,
    const float* __restrict__ table,
    const float* __restrict__ W_num,
    const float* __restrict__ bias,
    float* __restrict__ out,
    int nrows)
{
    __shared__ float tab[SROWS * SSTR];   // 62,064 B
    __shared__ float f4buf[RPP * 16];     // 16,384 B: pass-1's f4 rows, DMA'd
    __shared__ float wsum[24];            // padded; wsum[23] = 0
    // total 78.5 KB -> 2 blocks/CU

    const int tid = threadIdx.x;
    const int rl  = tid >> 2;   // local row within pass
    const int g   = tid & 3;    // dim-group: dims [4g, 4g+4)
    const int wb  = 6 * g;

    const int row0 = blockIdx.x * RPB + rl;    // grid*RPB == nrows, no guards
    const int row1 = row0 + RPP;

    // ===== PROLOGUE (register-light: ~29 live across staging, R11-proven) =====
    const int* xc0 = x_cat + (size_t)row0 * NF;
    const int4u av = *(const int4u*)(xc0 + g * 4);
    const int  a16 = xc0[16];
    const int* xc1 = x_cat + (size_t)row1 * NF;
    const int4u cv = *(const int4u*)(xc1 + g * 4);
    const int  c16 = xc1[16];

    // pass-0's 3 gathers: issue pre-staging (12 result regs, proven safe)
    const int bc4  = SWZ(av.x, 1);   // f4  (k=4:  slot x, lane 1)
    const int bc10 = SWZ(av.z, 2);   // f10 (k=10: slot z, lane 2)
    const int bc14 = SWZ(av.z, 3);   // f14 (k=14: slot z, lane 3)
    const float4 gv00 = *(const float4*)(table + (size_t)(bc4  +     653) * ED + g * 4);
    const float4 gv01 = *(const float4*)(table + (size_t)(bc10 + 1000787) * ED + g * 4);
    const float4 gv02 = *(const float4*)(table + (size_t)(bc14 + 1001846) * ED + g * 4);

    // pass-1's f4 (L3-latency): DMA straight to LDS — ZERO result registers.
    // dest is lane-linear (tid*16B) as required; barrier drains the DMA.
    {
        const int dc4 = SWZ(cv.x, 1);
        const float* src = table + (size_t)(dc4 + 653) * ED + g * 4;
        __builtin_amdgcn_global_load_lds(
            (const __attribute__((address_space(1))) void*)src,
            (__attribute__((address_space(3))) void*)&f4buf[tid * 4], 16, 0, 0);
    }

    // pass-0 numeric slice
    const float* xp0 = x_num + (size_t)row0 * NN;
    const float4u xa0 = *(const float4u*)(xp0 + wb);
    float xb0_0, xb1_0;
    if (g < 3) { const float2u t = *(const float2u*)(xp0 + wb + 4); xb0_0 = t.x; xb1_0 = t.y; }
    else       { xb0_0 = xp0[22]; xb1_0 = 0.f; }

    if (tid < 24) {
        float a = 0.f;
        if (tid < NN) {
            #pragma unroll
            for (int d = 0; d < ED; ++d) a += W_num[d * NN + tid];
        }
        wsum[tid] = a;
    }

    // ---- Stage the 14 small-vocab fields (862 rows): simple loop, SSTR=18 ----
    for (int i = tid; i < SROWS * 4; i += BLK) {
        const int r = i >> 2, q = i & 3;
        const int d = (r < 653) ? 0 : (r < 787) ? 1000000 : (r < 845) ? 1001001 : 1003001;
        *(float4*)&tab[r * SSTR + q * 4] =
            *(const float4*)(table + (size_t)(r + d) * ED + q * 4);
    }
    __syncthreads();   // drains staging, gv0x, and the f4buf DMA

    const float b0 = bias[0];
    const float2v wp0 = {wsum[wb],     wsum[wb + 1]};
    const float2v wp1 = {wsum[wb + 2], wsum[wb + 3]};
    const float2v wp2 = {wsum[wb + 4], wsum[wb + 5]};

    // ========== PASS 0 ==========
    {
        float2v lv = {0.f, 0.f};
        lv += float2v{xa0.x, xa0.y} * wp0;
        lv += float2v{xa0.z, xa0.w} * wp1;
        lv += float2v{xb0_0, xb1_0} * wp2;

        int pr[14];
        pr[0]  = SWZ(av.x, 0);         pr[1]  = 500 + SWZ(av.y, 0);
        pr[2]  = 550 + SWZ(av.z, 0);   pr[3]  = 650 + SWZ(av.w, 0);
        pr[4]  = 653 + SWZ(av.y, 1);   pr[5]  = 663 + SWZ(av.z, 1);
        pr[6]  = 683 + SWZ(av.w, 1);   pr[7]  = 783 + SWZ(av.x, 2);
        pr[8]  = 785 + SWZ(av.y, 2);   pr[9]  = 787 + SWZ(av.w, 2);
        pr[10] = 791 + SWZ(av.x, 3);   pr[11] = 795 + SWZ(av.y, 3);
        pr[12] = 845 + SWZ(av.w, 3);   pr[13] = 855 + a16;

        float2v sa = {0.f, 0.f}, sb = {0.f, 0.f}, sq2 = {0.f, 0.f};
        #pragma unroll
        for (int k = 0; k < 14; ++k)
            acc4(*(const float4*)&tab[pr[k] * SSTR + g * 4], sa, sb, sq2);

        acc4(gv00, sa, sb, sq2);
        acc4(gv01, sa, sb, sq2);
        acc4(gv02, sa, sb, sq2);

        const float s0 = sa.x, s1 = sa.y, s2 = sb.x, s3 = sb.y;
        const float sq = sq2.x + sq2.y;
        float contrib = (s0 + s1 + s2 + s3) + (lv.x + lv.y)
                      + 0.5f * ((s0 * s0 + s1 * s1 + s2 * s2 + s3 * s3) - sq);
        contrib += __shfl_xor(contrib, 1);
        contrib += __shfl_xor(contrib, 2);
        if (g == 0) out[row0] = b0 + contrib;
    }

    // ---- Pass-1 residual gathers (f10/f14, L2-hot ~200cyc) + x_num ----
    const int dc10 = SWZ(cv.z, 2);
    const int dc14 = SWZ(cv.z, 3);
    const float4 gv11 = *(const float4*)(table + (size_t)(dc10 + 1000787) * ED + g * 4);
    const float4 gv12 = *(const float4*)(table + (size_t)(dc14 + 1001846) * ED + g * 4);

    const float* xp1 = x_num + (size_t)row1 * NN;
    const float4u xa1 = *(const float4u*)(xp1 + wb);
    float xb0_1, xb1_1;
    if (g < 3) { const float2u t = *(const float2u*)(xp1 + wb + 4); xb0_1 = t.x; xb1_1 = t.y; }
    else       { xb0_1 = xp1[22]; xb1_1 = 0.f; }

    // ========== PASS 1 (f4 from LDS — zero exposed latency) ==========
    {
        int pr[14];
        pr[0]  = SWZ(cv.x, 0);         pr[1]  = 500 + SWZ(cv.y, 0);
        pr[2]  = 550 + SWZ(cv.z, 0);   pr[3]  = 650 + SWZ(cv.w, 0);
        pr[4]  = 653 + SWZ(cv.y, 1);   pr[5]  = 663 + SWZ(cv.z, 1);
        pr[6]  = 683 + SWZ(cv.w, 1);   pr[7]  = 783 + SWZ(cv.x, 2);
        pr[8]  = 785 + SWZ(cv.y, 2);   pr[9]  = 787 + SWZ(cv.w, 2);
        pr[10] = 791 + SWZ(cv.x, 3);   pr[11] = 795 + SWZ(cv.y, 3);
        pr[12] = 845 + SWZ(cv.w, 3);   pr[13] = 855 + c16;

        float2v lv = {0.f, 0.f};
        lv += float2v{xa1.x, xa1.y} * wp0;
        lv += float2v{xa1.z, xa1.w} * wp1;
        lv += float2v{xb0_1, xb1_1} * wp2;

        float2v sa = {0.f, 0.f}, sb = {0.f, 0.f}, sq2 = {0.f, 0.f};
        #pragma unroll
        for (int k = 0; k < 14; ++k)
            acc4(*(const float4*)&tab[pr[k] * SSTR + g * 4], sa, sb, sq2);

        const float4 fv1 = *(const float4*)&f4buf[tid * 4];   // pass-1 f4
        acc4(fv1, sa, sb, sq2);
        acc4(gv11, sa, sb, sq2);
        acc4(gv12, sa, sb, sq2);

        const float s0 = sa.x, s1 = sa.y, s2 = sb.x, s3 = sb.y;
        const float sq = sq2.x + sq2.y;
        float contrib = (s0 + s1 + s2 + s3) + (lv.x + lv.y)
                      + 0.5f * ((s0 * s0 + s1 * s1 + s2 * s2 + s3 * s3) - sq);
        contrib += __shfl_xor(contrib, 1);
        contrib += __shfl_xor(contrib, 2);
        if (g == 0) out[row1] = b0 + contrib;
    }
}

extern "C" void kernel_launch(void* const* d_in, const int* in_sizes, int n_in,
                              void* d_out, int out_size, void* d_ws, size_t ws_size,
                              hipStream_t stream) {
    const int*   x_cat = (const int*)  d_in[0];
    const float* x_num = (const float*)d_in[1];
    const float* table = (const float*)d_in[2];
    const float* W_num = (const float*)d_in[3];
    const float* bias  = (const float*)d_in[4];
    float* out = (float*)d_out;

    const int nrows = out_size;                 // 262144
    const int grid = (nrows + RPB - 1) / RPB;   // 512
    ffm_fwd_kernel<<<grid, BLK, 0, stream>>>(x_cat, x_num, table, W_num, bias, out, nrows);
}

// Round 18
// 18.036 us; speedup vs baseline: 1.5518x; 1.2459x over previous
//
#include <hip/hip_runtime.h>

#define NF 17
#define NN 23
#define ED 16
#define BLK 1024
#define RPP 256      // rows per pass = BLK/4
#define RPB 512      // rows per block (2 passes); grid*RPB == nrows exactly
#define SROWS 862    // packed rows of the 14 small-vocab fields
#define SSTR 20      // padded floats per LDS row (80 B)

typedef int   int4u    __attribute__((ext_vector_type(4), aligned(4)));
typedef float float4u  __attribute__((ext_vector_type(4), aligned(4)));
typedef float float2u  __attribute__((ext_vector_type(2), aligned(4)));
typedef float float2v  __attribute__((ext_vector_type(2)));

// packed accumulate: 2x v_pk_add_f32 + 2x v_pk_fma_f32 per field
__device__ __forceinline__ void acc4(const float4 v, float2v& sa, float2v& sb,
                                     float2v& sq2) {
    const float2v lo = {v.x, v.y};
    const float2v hi = {v.z, v.w};
    sa += lo;
    sb += hi;
    sq2 += lo * lo;
    sq2 += hi * hi;
}

__global__ __launch_bounds__(BLK, 8) void ffm_fwd_kernel(
    const int* __restrict__ x_cat,
    const float* __restrict__ x_num,
    const float* __restrict__ table,
    const float* __restrict__ W_num,
    const float* __restrict__ bias,
    float* __restrict__ out,
    int nrows)
{
    __shared__ float tab[SROWS * SSTR];   // 68,960 B -> 2 blocks/CU
    __shared__ float wsum[24];            // padded; wsum[23] = 0

    const int tid = threadIdx.x;
    const int rl  = tid >> 2;   // local row within pass
    const int g   = tid & 3;    // dim-group: dims [4g, 4g+4)
    const int wb  = 6 * g;

    const int row0 = blockIdx.x * RPB + rl;    // grid*RPB == nrows, no guards
    const int row1 = row0 + RPP;

    // ---- Pass-0 prefetch BEFORE staging: x_cat, then its 3 gathers ----
    const int* xc0 = x_cat + (size_t)row0 * NF;
    const int4u a0 = *(const int4u*)(xc0);
    const int4u a1 = *(const int4u*)(xc0 + 4);
    const int4u a2 = *(const int4u*)(xc0 + 8);
    const int4u a3 = *(const int4u*)(xc0 + 12);
    const int  a16 = xc0[16];
    const float4 gv00 = *(const float4*)(table + (size_t)(a1.x +     653) * ED + g * 4);
    const float4 gv01 = *(const float4*)(table + (size_t)(a2.z + 1000787) * ED + g * 4);
    const float4 gv02 = *(const float4*)(table + (size_t)(a3.z + 1001846) * ED + g * 4);

    const float* xp0 = x_num + (size_t)row0 * NN;
    const float4u xa0 = *(const float4u*)(xp0 + wb);
    float xb0_0, xb1_0;
    if (g < 3) { const float2u t = *(const float2u*)(xp0 + wb + 4); xb0_0 = t.x; xb1_0 = t.y; }
    else       { xb0_0 = xp0[22]; xb1_0 = 0.f; }

    if (tid < 24) {
        float a = 0.f;
        if (tid < NN) {
            #pragma unroll
            for (int d = 0; d < ED; ++d) a += W_num[d * NN + tid];
        }
        wsum[tid] = a;
    }

    // ---- Stage the 14 small-vocab fields (862 rows, 55 KB) once per block ----
    for (int i = tid; i < SROWS * 4; i += BLK) {
        const int r = i >> 2, q = i & 3;
        const int d = (r < 653) ? 0 : (r < 787) ? 1000000 : (r < 845) ? 1001001 : 1003001;
        *(float4*)&tab[r * SSTR + q * 4] =
            *(const float4*)(table + (size_t)(r + d) * ED + q * 4);
    }
    __syncthreads();

    const float b0 = bias[0];
    // packed wsum slice for dims [6g, 6g+6)
    const float2v wp0 = {wsum[wb],     wsum[wb + 1]};
    const float2v wp1 = {wsum[wb + 2], wsum[wb + 3]};
    const float2v wp2 = {wsum[wb + 4], wsum[wb + 5]};

    // ---- Prefetch pass-1 indices ----
    const int* xc1 = x_cat + (size_t)row1 * NF;
    const int4u c0 = *(const int4u*)(xc1);
    const int4u c1 = *(const int4u*)(xc1 + 4);
    const int4u c2 = *(const int4u*)(xc1 + 8);
    const int4u c3 = *(const int4u*)(xc1 + 12);
    const int  c16 = xc1[16];

    // ---- Pass 0 math ----
    {
        float2v lv = {0.f, 0.f};
        lv += float2v{xa0.x, xa0.y} * wp0;
        lv += float2v{xa0.z, xa0.w} * wp1;
        lv += float2v{xb0_0, xb1_0} * wp2;

        int pr[14];
        pr[0]  = a0.x;        pr[1]  = 500 + a0.y;  pr[2]  = 550 + a0.z;
        pr[3]  = 650 + a0.w;  pr[4]  = 653 + a1.y;  pr[5]  = 663 + a1.z;
        pr[6]  = 683 + a1.w;  pr[7]  = 783 + a2.x;  pr[8]  = 785 + a2.y;
        pr[9]  = 787 + a2.w;  pr[10] = 791 + a3.x;  pr[11] = 795 + a3.y;
        pr[12] = 845 + a3.w;  pr[13] = 855 + a16;

        float2v sa = {0.f, 0.f}, sb = {0.f, 0.f}, sq2 = {0.f, 0.f};
        #pragma unroll
        for (int k = 0; k < 14; ++k)
            acc4(*(const float4*)&tab[pr[k] * SSTR + g * 4], sa, sb, sq2);

        acc4(gv00, sa, sb, sq2);
        acc4(gv01, sa, sb, sq2);
        acc4(gv02, sa, sb, sq2);

        const float s0 = sa.x, s1 = sa.y, s2 = sb.x, s3 = sb.y;
        const float sq = sq2.x + sq2.y;
        float contrib = (s0 + s1 + s2 + s3) + (lv.x + lv.y)
                      + 0.5f * ((s0 * s0 + s1 * s1 + s2 * s2 + s3 * s3) - sq);
        contrib += __shfl_xor(contrib, 1);
        contrib += __shfl_xor(contrib, 2);
        if (g == 0) out[row0] = b0 + contrib;
    }

    // ---- Pass-1 gathers (indices already resident) + x_num ----
    const float4 gv10 = *(const float4*)(table + (size_t)(c1.x +     653) * ED + g * 4);
    const float4 gv11 = *(const float4*)(table + (size_t)(c2.z + 1000787) * ED + g * 4);
    const float4 gv12 = *(const float4*)(table + (size_t)(c3.z + 1001846) * ED + g * 4);

    const float* xp1 = x_num + (size_t)row1 * NN;
    const float4u xa1 = *(const float4u*)(xp1 + wb);
    float xb0_1, xb1_1;
    if (g < 3) { const float2u t = *(const float2u*)(xp1 + wb + 4); xb0_1 = t.x; xb1_1 = t.y; }
    else       { xb0_1 = xp1[22]; xb1_1 = 0.f; }

    // ---- Pass 1 math ----
    {
        float2v lv = {0.f, 0.f};
        lv += float2v{xa1.x, xa1.y} * wp0;
        lv += float2v{xa1.z, xa1.w} * wp1;
        lv += float2v{xb0_1, xb1_1} * wp2;

        int pr[14];
        pr[0]  = c0.x;        pr[1]  = 500 + c0.y;  pr[2]  = 550 + c0.z;
        pr[3]  = 650 + c0.w;  pr[4]  = 653 + c1.y;  pr[5]  = 663 + c1.z;
        pr[6]  = 683 + c1.w;  pr[7]  = 783 + c2.x;  pr[8]  = 785 + c2.y;
        pr[9]  = 787 + c2.w;  pr[10] = 791 + c3.x;  pr[11] = 795 + c3.y;
        pr[12] = 845 + c3.w;  pr[13] = 855 + c16;

        float2v sa = {0.f, 0.f}, sb = {0.f, 0.f}, sq2 = {0.f, 0.f};
        #pragma unroll
        for (int k = 0; k < 14; ++k)
            acc4(*(const float4*)&tab[pr[k] * SSTR + g * 4], sa, sb, sq2);

        acc4(gv10, sa, sb, sq2);
        acc4(gv11, sa, sb, sq2);
        acc4(gv12, sa, sb, sq2);

        const float s0 = sa.x, s1 = sa.y, s2 = sb.x, s3 = sb.y;
        const float sq = sq2.x + sq2.y;
        float contrib = (s0 + s1 + s2 + s3) + (lv.x + lv.y)
                      + 0.5f * ((s0 * s0 + s1 * s1 + s2 * s2 + s3 * s3) - sq);
        contrib += __shfl_xor(contrib, 1);
        contrib += __shfl_xor(contrib, 2);
        if (g == 0) out[row1] = b0 + contrib;
    }
}

extern "C" void kernel_launch(void* const* d_in, const int* in_sizes, int n_in,
                              void* d_out, int out_size, void* d_ws, size_t ws_size,
                              hipStream_t stream) {
    const int*   x_cat = (const int*)  d_in[0];
    const float* x_num = (const float*)d_in[1];
    const float* table = (const float*)d_in[2];
    const float* W_num = (const float*)d_in[3];
    const float* bias  = (const float*)d_in[4];
    float* out = (float*)d_out;

    const int nrows = out_size;                 // 262144
    const int grid = (nrows + RPB - 1) / RPB;   // 512
    ffm_fwd_kernel<<<grid, BLK, 0, stream>>>(x_cat, x_num, table, W_num, bias, out, nrows);
}